// Round 15
// baseline (457.786 us; speedup 1.0000x reference)
//
#include <hip/hip_runtime.h>

#define DIM   64
#define G3    192      // 3*DIM
#define NB    512      // BATCH
#define NM    32       // N_MEM
#define NRELS 32
#define CH    32       // GI chunk (steps) staged in LDS
#define NCH   (NB/CH)
#define KGE_W 0.01f
#define L2_W  1e-7f
#define EPSC  1e-7f

// ---------- helpers ----------

__device__ inline float bcast(float v, int srclane) {
    return __int_as_float(__builtin_amdgcn_readlane(__float_as_int(v), srclane));
}

__device__ inline float sigmoidf_(float x) { return 1.0f / (1.0f + __expf(-x)); }
__device__ inline float tanhf_(float x)    { return 1.0f - 2.0f / (1.0f + __expf(2.0f * x)); }

__device__ inline float wave_sum(float v) {
#pragma unroll
    for (int off = 32; off > 0; off >>= 1) v += __shfl_xor(v, off, 64);
    return v;
}
__device__ inline float wave_max(float v) {
#pragma unroll
    for (int off = 32; off > 0; off >>= 1) v = fmaxf(v, __shfl_xor(v, off, 64));
    return v;
}

// ---------- X-macros ----------

#define FOR32(F) F(0)F(1)F(2)F(3)F(4)F(5)F(6)F(7)F(8)F(9)F(10)F(11)F(12)F(13)F(14)F(15) \
                 F(16)F(17)F(18)F(19)F(20)F(21)F(22)F(23)F(24)F(25)F(26)F(27)F(28)F(29)F(30)F(31)
#define FOR8_0(F) F(0)F(1)F(2)F(3)F(4)F(5)F(6)F(7)
#define FOR8_1(F) F(8)F(9)F(10)F(11)F(12)F(13)F(14)F(15)
#define FOR8_2(F) F(16)F(17)F(18)F(19)F(20)F(21)F(22)F(23)
#define FOR8_3(F) F(24)F(25)F(26)F(27)F(28)F(29)F(30)F(31)

// f32 -> f16 (RTE) bit pattern
#define F16U(x) ((unsigned)__builtin_bit_cast(unsigned short, (_Float16)(x)))

// ---------- GRU: LDS-staged GI in, LDS-staged ys out; permlane h-broadcast ----------
// R14 structure, single change: dot accumulators split 12 ways (4 chains x
// 8-deep per gate) to halve dependency-chain depth at equal instruction count.

__device__ __forceinline__ void gru_scan_staged(float (*gibuf)[CH * G3],   // [2][CH*192] LDS
                                                float (*ysbuf)[CH * DIM],  // [2][CH*64]  LDS
                                                const float* __restrict__ GI,   // [NB][192]
                                                const float* __restrict__ whh,  // [192][64]
                                                const float* __restrict__ bhh,  // [192]
                                                const float* __restrict__ h0,   // [64] or nullptr
                                                float* __restrict__ ys,         // [NB][64]
                                                float* __restrict__ hfin_out)   // [64] or nullptr
{
    const int tid  = threadIdx.x;
    const int lane = tid & 63;
    const int wave = tid >> 6;

    // prologue: stage chunk 0 into buffer 0
    if (wave != 0) {
        const int sid = tid - 64;                    // 0..191
        const float4* src = (const float4*)GI;
        float4* dst = (float4*)gibuf[0];
#pragma unroll
        for (int j = 0; j < 8; ++j) dst[sid + j * 192] = src[sid + j * 192];
    }
    __syncthreads();

    if (wave == 0) {
        const float* wrp = whh + (0 * DIM + lane) * DIM;
        const float* wzp = whh + (1 * DIM + lane) * DIM;
        const float* wnp = whh + (2 * DIM + lane) * DIM;

        // 96 packed f16x2 weight pairs, paired (k=j, k=j+32)
#define DWP(j) unsigned uwr##j, uwz##j, uwn##j;
        FOR32(DWP)
#undef DWP
#define LWP(j) uwr##j = F16U(wrp[(j)]) | (F16U(wrp[(j)+32]) << 16); \
               uwz##j = F16U(wzp[(j)]) | (F16U(wzp[(j)+32]) << 16); \
               uwn##j = F16U(wnp[(j)]) | (F16U(wnp[(j)+32]) << 16);
        FOR32(LWP)
#undef LWP

        const float br = bhh[lane], bz = bhh[DIM + lane], bn = bhh[2 * DIM + lane];
        float h = h0 ? h0[lane] : 0.0f;

        for (int c = 0; c < NCH; ++c) {
            const float* buf = gibuf[c & 1];
            float* yb = ysbuf[c & 1];
            for (int tl = 0; tl < CH; ++tl) {
                const float* gi = buf + tl * G3;
                float c0 = gi[lane], c1 = gi[DIM + lane], c2 = gi[2 * DIM + lane];  // ds_read (used late)

                // DS-free pack: lane j<32 ends with A=h_j, B=h_{j+32}
                float A = h, B = h;
                asm("v_permlane32_swap_b32 %0, %1" : "+v"(A), "+v"(B));
                unsigned packed = __builtin_bit_cast(unsigned,
                                     __builtin_amdgcn_cvt_pkrtz(A, B));

                // 32 broadcasts into SGPRs
#define RL(j) unsigned hp##j = (unsigned)__builtin_amdgcn_readlane((int)packed, j);
                FOR32(RL)
#undef RL

                float ar0 = br, ar1 = 0.f, ar2 = 0.f, ar3 = 0.f;
                float az0 = bz, az1 = 0.f, az2 = 0.f, az3 = 0.f;
                float an0 = bn, an1 = 0.f, an2 = 0.f, an3 = 0.f;
#define SJA(j) { asm("v_dot2_f32_f16 %0, %1, %2, %0" : "+v"(ar0) : "v"(uwr##j), "s"(hp##j)); \
                 asm("v_dot2_f32_f16 %0, %1, %2, %0" : "+v"(az0) : "v"(uwz##j), "s"(hp##j)); \
                 asm("v_dot2_f32_f16 %0, %1, %2, %0" : "+v"(an0) : "v"(uwn##j), "s"(hp##j)); }
                FOR8_0(SJA)
#undef SJA
#define SJB(j) { asm("v_dot2_f32_f16 %0, %1, %2, %0" : "+v"(ar1) : "v"(uwr##j), "s"(hp##j)); \
                 asm("v_dot2_f32_f16 %0, %1, %2, %0" : "+v"(az1) : "v"(uwz##j), "s"(hp##j)); \
                 asm("v_dot2_f32_f16 %0, %1, %2, %0" : "+v"(an1) : "v"(uwn##j), "s"(hp##j)); }
                FOR8_1(SJB)
#undef SJB
#define SJC(j) { asm("v_dot2_f32_f16 %0, %1, %2, %0" : "+v"(ar2) : "v"(uwr##j), "s"(hp##j)); \
                 asm("v_dot2_f32_f16 %0, %1, %2, %0" : "+v"(az2) : "v"(uwz##j), "s"(hp##j)); \
                 asm("v_dot2_f32_f16 %0, %1, %2, %0" : "+v"(an2) : "v"(uwn##j), "s"(hp##j)); }
                FOR8_2(SJC)
#undef SJC
#define SJD(j) { asm("v_dot2_f32_f16 %0, %1, %2, %0" : "+v"(ar3) : "v"(uwr##j), "s"(hp##j)); \
                 asm("v_dot2_f32_f16 %0, %1, %2, %0" : "+v"(az3) : "v"(uwz##j), "s"(hp##j)); \
                 asm("v_dot2_f32_f16 %0, %1, %2, %0" : "+v"(an3) : "v"(uwn##j), "s"(hp##j)); }
                FOR8_3(SJD)
#undef SJD

                float ghr = (ar0 + ar1) + (ar2 + ar3);
                float ghz = (az0 + az1) + (az2 + az3);
                float ghn = (an0 + an1) + (an2 + an3);

                float r = sigmoidf_(c0 + ghr);
                float z = sigmoidf_(c1 + ghz);
                float n = tanhf_(c2 + r * ghn);
                h = n + z * (h - n);               // (1-z)*n + z*h

                yb[tl * DIM + lane] = h;           // ds_write (stagers flush to global)
            }
            __syncthreads();                        // chunk boundary
        }
        if (hfin_out) hfin_out[lane] = h;
    } else {
        const int sid = tid - 64;                    // 0..191

        auto flush_ys = [&](int cc) {
            const float4* src = (const float4*)ysbuf[cc & 1];
            float4* dst = (float4*)(ys + (size_t)cc * CH * DIM);
            for (int j = sid; j < CH * DIM / 4; j += 192) dst[j] = src[j];
        };

        for (int c = 0; c < NCH; ++c) {
            if (c + 1 < NCH) {
                const float4* src = (const float4*)(GI + (size_t)(c + 1) * CH * G3);
                float4* dst = (float4*)gibuf[(c + 1) & 1];
#pragma unroll
                for (int j = 0; j < 8; ++j) dst[sid + j * 192] = src[sid + j * 192];
            }
            if (c >= 1) flush_ys(c - 1);             // chunk c-1 visible after barrier c-1
            __syncthreads();
        }
        flush_ys(NCH - 1);                           // last chunk after final barrier
    }
}

// ---------- gi: GI = wih @ x + bih (+ per-relation sqnorm on extra blocks) ----------

__global__ __launch_bounds__(64) void gi_kernel(const float* __restrict__ xsrc,
                                                const int* __restrict__ idx,    // nullptr => direct
                                                const float* __restrict__ wih,  // [192][64]
                                                const float* __restrict__ bih,  // [192]
                                                const float* __restrict__ Rel,  // [32][4096]
                                                float* __restrict__ GI,         // [NB][192]
                                                float* __restrict__ relnorm)    // [32]
{
    const int blk = blockIdx.x, lane = threadIdx.x;
    if (blk >= NB) {
        const int r = blk - NB;
        const float* R = Rel + r * DIM * DIM;
        float a = 0.0f;
#pragma unroll 4
        for (int i = 0; i < DIM; ++i) { float v = R[i * DIM + lane]; a = fmaf(v, v, a); }
        a = wave_sum(a);
        if (lane == 0) relnorm[r] = a;
        return;
    }
    const int b = blk;
    float xv = idx ? xsrc[idx[b] * DIM + lane] : xsrc[b * DIM + lane];
    float a0 = bih[lane], a1 = bih[DIM + lane], a2 = bih[2 * DIM + lane];
    const float* w0 = wih + (0 * DIM + lane) * DIM;
    const float* w1 = wih + (1 * DIM + lane) * DIM;
    const float* w2 = wih + (2 * DIM + lane) * DIM;
#pragma unroll 4
    for (int k = 0; k < DIM; ++k) {
        float xk = bcast(xv, k);
        a0 = fmaf(w0[k], xk, a0);
        a1 = fmaf(w1[k], xk, a1);
        a2 = fmaf(w2[k], xk, a2);
    }
    float* gp = GI + b * G3;
    gp[lane] = a0; gp[DIM + lane] = a1; gp[2 * DIM + lane] = a2;
}

// ---------- fused0: block 0 = GRU hop0 (staged); blocks 1..512 = att hop0 + KGE + L2 ----------

__global__ __launch_bounds__(256, 1) void fused0(const float* __restrict__ E,
                                              const float* __restrict__ Rel,
                                              const int* __restrict__ items,
                                              const int* __restrict__ mh,
                                              const int* __restrict__ mr,
                                              const int* __restrict__ mt,
                                              const float* __restrict__ GI,
                                              const float* __restrict__ whh,
                                              const float* __restrict__ bhh,
                                              const float* __restrict__ relnorm,
                                              float* __restrict__ ys0,
                                              float* __restrict__ hfin,
                                              float* __restrict__ o0,
                                              float* __restrict__ kge_part,   // [NB][2]
                                              float* __restrict__ l2_part)    // [NB]
{
    __shared__ __align__(16) float gibuf[2][CH * G3];   // 48 KiB
    __shared__ __align__(16) float ysbuf[2][CH * DIM];  // 16 KiB
    __shared__ float logits[NM], probs[NM], opart[4][DIM], wred[4][4];

    if (blockIdx.x == 0) {
        gru_scan_staged(gibuf, ysbuf, GI, whh, bhh, nullptr, ys0, hfin);
        return;
    }

    const int b = blockIdx.x - 1;
    const int tid = threadIdx.x, lane = tid & 63, wave = tid >> 6;

    float iv = E[items[b] * DIM + lane];
    float kge0 = 0.0f, kge1 = 0.0f, l2acc = 0.0f, r2acc = 0.0f;

    for (int mm = 0; mm < 8; ++mm) {
        const int m = wave * 8 + mm;
        const int base = b * NM + m;                 // hop 0
        const int hidx = mh[base], ridx = mr[base], tidx = mt[base];
        float hv = E[hidx * DIM + lane];
        float tv = E[tidx * DIM + lane];
        l2acc = fmaf(hv, hv, l2acc);
        l2acc = fmaf(tv, tv, l2acc);
        r2acc += relnorm[ridx];
        const float* R = Rel + ridx * DIM * DIM;
        float accA = 0.0f, accK = 0.0f;
#pragma unroll 4
        for (int i = 0; i < DIM; ++i) {
            float rv = R[i * DIM + lane];
            accA = fmaf(bcast(iv, i), rv, accA);
            accK = fmaf(bcast(hv, i), rv, accK);
        }
        float la = wave_sum(accA * hv);              // item^T R h
        float lk = wave_sum(accK * tv);              // h^T R t
        if (lane == 0) logits[m] = la;
        kge0 += sigmoidf_(lk);
    }
    for (int mm = 0; mm < 8; ++mm) {
        const int m = wave * 8 + mm;
        const int base = NB * NM + b * NM + m;       // hop 1
        const int hidx = mh[base], ridx = mr[base], tidx = mt[base];
        float hv = E[hidx * DIM + lane];
        float tv = E[tidx * DIM + lane];
        l2acc = fmaf(hv, hv, l2acc);
        l2acc = fmaf(tv, tv, l2acc);
        r2acc += relnorm[ridx];
        const float* R = Rel + ridx * DIM * DIM;
        float accK = 0.0f;
#pragma unroll 4
        for (int i = 0; i < DIM; ++i)
            accK = fmaf(bcast(hv, i), R[i * DIM + lane], accK);
        kge1 += sigmoidf_(wave_sum(accK * tv));
    }
    __syncthreads();

    if (wave == 0) {
        float v = (lane < NM) ? logits[lane] : -1e30f;
        float mx = wave_max(v);
        float e = (lane < NM) ? __expf(v - mx) : 0.0f;
        float ssum = wave_sum(e);
        if (lane < NM) probs[lane] = e / ssum;
    }
    __syncthreads();

    float od = 0.0f;
    for (int mm = 0; mm < 8; ++mm) {
        const int m = wave * 8 + mm;
        const int tidx = mt[b * NM + m];
        od = fmaf(probs[m], E[tidx * DIM + lane], od);
    }
    opart[wave][lane] = od;
    float l2tot = wave_sum(l2acc);
    if (lane == 0) { wred[wave][0] = kge0; wred[wave][1] = kge1; wred[wave][2] = l2tot + r2acc; }
    __syncthreads();
    if (wave == 0)
        o0[b * DIM + lane] = opart[0][lane] + opart[1][lane] + opart[2][lane] + opart[3][lane];
    if (tid == 0) {
        kge_part[b * 2 + 0] = wred[0][0] + wred[1][0] + wred[2][0] + wred[3][0];
        kge_part[b * 2 + 1] = wred[0][1] + wred[1][1] + wred[2][1] + wred[3][1];
        l2_part[b]          = wred[0][2] + wred[1][2] + wred[2][2] + wred[3][2];
    }
}

// ---------- fused1: block 0 = GRU hop1 (staged); blocks 1..512 = att hop1 + o_sum ----------

__global__ __launch_bounds__(256, 1) void fused1(const float* __restrict__ E,
                                              const float* __restrict__ Rel,
                                              const int* __restrict__ mh,
                                              const int* __restrict__ mr,
                                              const int* __restrict__ mt,
                                              const float* __restrict__ GI,
                                              const float* __restrict__ whh,
                                              const float* __restrict__ bhh,
                                              const float* __restrict__ hfin,
                                              const float* __restrict__ ys0,
                                              float* __restrict__ ys1,
                                              const float* __restrict__ o0,
                                              float* __restrict__ osum)
{
    __shared__ __align__(16) float gibuf[2][CH * G3];   // 48 KiB
    __shared__ __align__(16) float ysbuf[2][CH * DIM];  // 16 KiB
    __shared__ float logits[NM], probs[NM], opart[4][DIM];

    if (blockIdx.x == 0) {
        gru_scan_staged(gibuf, ysbuf, GI, whh, bhh, hfin, ys1, nullptr);
        return;
    }

    const int b = blockIdx.x - 1;
    const int tid = threadIdx.x, lane = tid & 63, wave = tid >> 6;

    float iv = ys0[b * DIM + lane];   // item_emb after 1 GRU pass

    for (int mm = 0; mm < 8; ++mm) {
        const int m = wave * 8 + mm;
        const int base = NB * NM + b * NM + m;       // hop 1
        const int hidx = mh[base], ridx = mr[base];
        float hv = E[hidx * DIM + lane];
        const float* R = Rel + ridx * DIM * DIM;
        float accA = 0.0f;
#pragma unroll 4
        for (int i = 0; i < DIM; ++i)
            accA = fmaf(bcast(iv, i), R[i * DIM + lane], accA);
        float la = wave_sum(accA * hv);
        if (lane == 0) logits[m] = la;
    }
    __syncthreads();
    if (wave == 0) {
        float v = (lane < NM) ? logits[lane] : -1e30f;
        float mx = wave_max(v);
        float e = (lane < NM) ? __expf(v - mx) : 0.0f;
        float ssum = wave_sum(e);
        if (lane < NM) probs[lane] = e / ssum;
    }
    __syncthreads();
    float od = 0.0f;
    for (int mm = 0; mm < 8; ++mm) {
        const int m = wave * 8 + mm;
        const int tidx = mt[NB * NM + b * NM + m];
        od = fmaf(probs[m], E[tidx * DIM + lane], od);
    }
    opart[wave][lane] = od;
    __syncthreads();
    if (wave == 0)
        osum[b * DIM + lane] = o0[b * DIM + lane] +
            opart[0][lane] + opart[1][lane] + opart[2][lane] + opart[3][lane];
}

// ---------- finalize: scores + losses ----------

__global__ __launch_bounds__(512) void finalize(const float* __restrict__ ys1,
                                                const float* __restrict__ osum,
                                                const int* __restrict__ labels,
                                                const float* __restrict__ kge_part,
                                                const float* __restrict__ l2_part,
                                                float* __restrict__ out)
{
    __shared__ float red[512];
    const int tid = threadIdx.x;

    float dot = 0.0f;
    const float* a = ys1 + tid * DIM;
    const float* c = osum + tid * DIM;
#pragma unroll 8
    for (int k = 0; k < DIM; ++k) dot = fmaf(a[k], c[k], dot);
    float score = sigmoidf_(dot);
    out[tid] = score;

    float s = fminf(fmaxf(score, EPSC), 1.0f - EPSC);
    float term = labels[tid] ? logf(s) : log1pf(-s);

    float bsum, ksum, lsum;
    {
        red[tid] = term; __syncthreads();
#pragma unroll
        for (int st = 256; st > 0; st >>= 1) { if (tid < st) red[tid] += red[tid + st]; __syncthreads(); }
        bsum = red[0]; __syncthreads();
    }
    {
        red[tid] = kge_part[2 * tid] + kge_part[2 * tid + 1]; __syncthreads();
#pragma unroll
        for (int st = 256; st > 0; st >>= 1) { if (tid < st) red[tid] += red[tid + st]; __syncthreads(); }
        ksum = red[0]; __syncthreads();
    }
    {
        red[tid] = l2_part[tid]; __syncthreads();
#pragma unroll
        for (int st = 256; st > 0; st >>= 1) { if (tid < st) red[tid] += red[tid + st]; __syncthreads(); }
        lsum = red[0];
    }

    if (tid == 0) {
        float base = -bsum / (float)NB;
        float kge  = -KGE_W * ksum / (float)(NB * NM);
        float l2   = L2_W * lsum;
        out[NB + 0] = base;
        out[NB + 1] = kge;
        out[NB + 2] = l2;
        out[NB + 3] = base + kge + l2;
    }
}

// ---------- host ----------

extern "C" void kernel_launch(void* const* d_in, const int* in_sizes, int n_in,
                              void* d_out, int out_size, void* d_ws, size_t ws_size,
                              hipStream_t stream) {
    const int*   items  = (const int*)d_in[0];
    const int*   labels = (const int*)d_in[1];
    const int*   mh     = (const int*)d_in[2];
    const int*   mr     = (const int*)d_in[3];
    const int*   mt     = (const int*)d_in[4];
    const float* E      = (const float*)d_in[5];
    const float* Rel    = (const float*)d_in[6];
    const float* wih    = (const float*)d_in[7];
    const float* whh    = (const float*)d_in[8];
    const float* bih    = (const float*)d_in[9];
    const float* bhh    = (const float*)d_in[10];
    float* out = (float*)d_out;
    float* ws  = (float*)d_ws;

    // workspace layout (floats)
    float* GI0     = ws;                 // 512*192 = 98304
    float* GI1     = GI0 + 98304;        // 98304
    float* ys0     = GI1 + 98304;        // 32768
    float* ys1     = ys0 + 32768;        // 32768
    float* hfin    = ys1 + 32768;        // 64
    float* o0      = hfin + 64;          // 32768
    float* osum    = o0 + 32768;         // 32768
    float* relnorm = osum + 32768;       // 32
    float* kge_p   = relnorm + 32;       // 1024
    float* l2_p    = kge_p + 1024;       // 512

    // gi0: GI for hop 0 (x = entity_emb[items]) + per-relation sqnorms
    gi_kernel<<<NB + NRELS, 64, 0, stream>>>(E, items, wih, bih, Rel, GI0, relnorm);
    // fused0: GRU hop0 (block 0, LDS in/out staging) || att hop0 + KGE + L2
    fused0<<<NB + 1, 256, 0, stream>>>(E, Rel, items, mh, mr, mt, GI0, whh, bhh,
                                       relnorm, ys0, hfin, o0, kge_p, l2_p);
    // gi1: GI for hop 1 (x = ys0)
    gi_kernel<<<NB, 64, 0, stream>>>(ys0, nullptr, wih, bih, Rel, GI1, relnorm);
    // fused1: GRU hop1 (block 0, LDS in/out staging) || att hop1 + o_sum
    fused1<<<NB + 1, 256, 0, stream>>>(E, Rel, mh, mr, mt, GI1, whh, bhh, hfin,
                                       ys0, ys1, o0, osum);
    // finalize: scores + losses
    finalize<<<1, 512, 0, stream>>>(ys1, osum, labels, kge_p, l2_p, out);
}

// Round 16
// 445.216 us; speedup vs baseline: 1.0282x; 1.0282x over previous
//
#include <hip/hip_runtime.h>

#define DIM   64
#define G3    192      // 3*DIM
#define NB    512      // BATCH
#define NM    32       // N_MEM
#define NRELS 32
#define CH    32       // GI chunk (steps) staged in LDS
#define NCH   (NB/CH)
#define KGE_W 0.01f
#define L2_W  1e-7f
#define EPSC  1e-7f

// ---------- helpers ----------

__device__ inline float bcast(float v, int srclane) {
    return __int_as_float(__builtin_amdgcn_readlane(__float_as_int(v), srclane));
}

__device__ inline float sigmoidf_(float x) { return 1.0f / (1.0f + __expf(-x)); }
__device__ inline float tanhf_(float x)    { return 1.0f - 2.0f / (1.0f + __expf(2.0f * x)); }

__device__ inline float wave_sum(float v) {
#pragma unroll
    for (int off = 32; off > 0; off >>= 1) v += __shfl_xor(v, off, 64);
    return v;
}
__device__ inline float wave_max(float v) {
#pragma unroll
    for (int off = 32; off > 0; off >>= 1) v = fmaxf(v, __shfl_xor(v, off, 64));
    return v;
}

// ---------- X-macros ----------

#define FOR32(F) F(0)F(1)F(2)F(3)F(4)F(5)F(6)F(7)F(8)F(9)F(10)F(11)F(12)F(13)F(14)F(15) \
                 F(16)F(17)F(18)F(19)F(20)F(21)F(22)F(23)F(24)F(25)F(26)F(27)F(28)F(29)F(30)F(31)
#define FOR16A(F) F(0)F(1)F(2)F(3)F(4)F(5)F(6)F(7)F(8)F(9)F(10)F(11)F(12)F(13)F(14)F(15)
#define FOR16B(F) F(16)F(17)F(18)F(19)F(20)F(21)F(22)F(23)F(24)F(25)F(26)F(27)F(28)F(29)F(30)F(31)

// f32 -> f16 (RTE) bit pattern
#define F16U(x) ((unsigned)__builtin_bit_cast(unsigned short, (_Float16)(x)))

// ---------- GRU: LDS-staged GI in, LDS-staged ys out; permlane h-broadcast ----------
// Wave 0: serial recurrence. Weights as 96 packed f16x2 VGPRs paired
// (k=j, k=j+32). Per step: one v_permlane32_swap_b32 + one v_cvt_pkrtz pack
// h; 32 v_readlane broadcasts; 96 v_dot2_f32_f16 (proven schedule — all
// dots in 6 chains, then gates); h_new -> ds_write to ysbuf (no global
// store in the serial loop). Waves 1-3: stage GI chunk c+1 into LDS AND
// copy ys chunk c-1 LDS->global, double-buffered, one barrier per chunk.

__device__ __forceinline__ void gru_scan_staged(float (*gibuf)[CH * G3],   // [2][CH*192] LDS
                                                float (*ysbuf)[CH * DIM],  // [2][CH*64]  LDS
                                                const float* __restrict__ GI,   // [NB][192]
                                                const float* __restrict__ whh,  // [192][64]
                                                const float* __restrict__ bhh,  // [192]
                                                const float* __restrict__ h0,   // [64] or nullptr
                                                float* __restrict__ ys,         // [NB][64]
                                                float* __restrict__ hfin_out)   // [64] or nullptr
{
    const int tid  = threadIdx.x;
    const int lane = tid & 63;
    const int wave = tid >> 6;

    // prologue: stage chunk 0 into buffer 0
    if (wave != 0) {
        const int sid = tid - 64;                    // 0..191
        const float4* src = (const float4*)GI;
        float4* dst = (float4*)gibuf[0];
#pragma unroll
        for (int j = 0; j < 8; ++j) dst[sid + j * 192] = src[sid + j * 192];
    }
    __syncthreads();

    if (wave == 0) {
        const float* wrp = whh + (0 * DIM + lane) * DIM;
        const float* wzp = whh + (1 * DIM + lane) * DIM;
        const float* wnp = whh + (2 * DIM + lane) * DIM;

        // 96 packed f16x2 weight pairs, paired (k=j, k=j+32)
#define DWP(j) unsigned uwr##j, uwz##j, uwn##j;
        FOR32(DWP)
#undef DWP
#define LWP(j) uwr##j = F16U(wrp[(j)]) | (F16U(wrp[(j)+32]) << 16); \
               uwz##j = F16U(wzp[(j)]) | (F16U(wzp[(j)+32]) << 16); \
               uwn##j = F16U(wnp[(j)]) | (F16U(wnp[(j)+32]) << 16);
        FOR32(LWP)
#undef LWP

        const float br = bhh[lane], bz = bhh[DIM + lane], bn = bhh[2 * DIM + lane];
        float h = h0 ? h0[lane] : 0.0f;

        for (int c = 0; c < NCH; ++c) {
            const float* buf = gibuf[c & 1];
            float* yb = ysbuf[c & 1];
            for (int tl = 0; tl < CH; ++tl) {
                const float* gi = buf + tl * G3;
                float c0 = gi[lane], c1 = gi[DIM + lane], c2 = gi[2 * DIM + lane];  // ds_read (used late)

                // DS-free pack: lane j<32 ends with A=h_j, B=h_{j+32}
                float A = h, B = h;
                asm("v_permlane32_swap_b32 %0, %1" : "+v"(A), "+v"(B));
                unsigned packed = __builtin_bit_cast(unsigned,
                                     __builtin_amdgcn_cvt_pkrtz(A, B));

                // 32 broadcasts into SGPRs
#define RL(j) unsigned hp##j = (unsigned)__builtin_amdgcn_readlane((int)packed, j);
                FOR32(RL)
#undef RL

                float ar0 = br, ar1 = 0.f, az0 = bz, az1 = 0.f, an0 = bn, an1 = 0.f;
#define SJ0(j) { asm("v_dot2_f32_f16 %0, %1, %2, %0" : "+v"(ar0) : "v"(uwr##j), "s"(hp##j)); \
                 asm("v_dot2_f32_f16 %0, %1, %2, %0" : "+v"(az0) : "v"(uwz##j), "s"(hp##j)); \
                 asm("v_dot2_f32_f16 %0, %1, %2, %0" : "+v"(an0) : "v"(uwn##j), "s"(hp##j)); }
                FOR16A(SJ0)
#undef SJ0
#define SJ1(j) { asm("v_dot2_f32_f16 %0, %1, %2, %0" : "+v"(ar1) : "v"(uwr##j), "s"(hp##j)); \
                 asm("v_dot2_f32_f16 %0, %1, %2, %0" : "+v"(az1) : "v"(uwz##j), "s"(hp##j)); \
                 asm("v_dot2_f32_f16 %0, %1, %2, %0" : "+v"(an1) : "v"(uwn##j), "s"(hp##j)); }
                FOR16B(SJ1)
#undef SJ1

                float ghr = ar0 + ar1;
                float ghz = az0 + az1;
                float ghn = an0 + an1;

                float r = sigmoidf_(c0 + ghr);
                float z = sigmoidf_(c1 + ghz);
                float n = tanhf_(c2 + r * ghn);
                h = n + z * (h - n);               // (1-z)*n + z*h

                yb[tl * DIM + lane] = h;           // ds_write (stagers flush to global)
            }
            __syncthreads();                        // chunk boundary
        }
        if (hfin_out) hfin_out[lane] = h;
    } else {
        const int sid = tid - 64;                    // 0..191

        auto flush_ys = [&](int cc) {
            const float4* src = (const float4*)ysbuf[cc & 1];
            float4* dst = (float4*)(ys + (size_t)cc * CH * DIM);
            for (int j = sid; j < CH * DIM / 4; j += 192) dst[j] = src[j];
        };

        for (int c = 0; c < NCH; ++c) {
            if (c + 1 < NCH) {
                const float4* src = (const float4*)(GI + (size_t)(c + 1) * CH * G3);
                float4* dst = (float4*)gibuf[(c + 1) & 1];
#pragma unroll
                for (int j = 0; j < 8; ++j) dst[sid + j * 192] = src[sid + j * 192];
            }
            if (c >= 1) flush_ys(c - 1);             // chunk c-1 visible after barrier c-1
            __syncthreads();
        }
        flush_ys(NCH - 1);                           // last chunk after final barrier
    }
}

// ---------- gi: GI = wih @ x + bih (+ per-relation sqnorm on extra blocks) ----------

__global__ __launch_bounds__(64) void gi_kernel(const float* __restrict__ xsrc,
                                                const int* __restrict__ idx,    // nullptr => direct
                                                const float* __restrict__ wih,  // [192][64]
                                                const float* __restrict__ bih,  // [192]
                                                const float* __restrict__ Rel,  // [32][4096]
                                                float* __restrict__ GI,         // [NB][192]
                                                float* __restrict__ relnorm)    // [32]
{
    const int blk = blockIdx.x, lane = threadIdx.x;
    if (blk >= NB) {
        const int r = blk - NB;
        const float* R = Rel + r * DIM * DIM;
        float a = 0.0f;
#pragma unroll 4
        for (int i = 0; i < DIM; ++i) { float v = R[i * DIM + lane]; a = fmaf(v, v, a); }
        a = wave_sum(a);
        if (lane == 0) relnorm[r] = a;
        return;
    }
    const int b = blk;
    float xv = idx ? xsrc[idx[b] * DIM + lane] : xsrc[b * DIM + lane];
    float a0 = bih[lane], a1 = bih[DIM + lane], a2 = bih[2 * DIM + lane];
    const float* w0 = wih + (0 * DIM + lane) * DIM;
    const float* w1 = wih + (1 * DIM + lane) * DIM;
    const float* w2 = wih + (2 * DIM + lane) * DIM;
#pragma unroll 4
    for (int k = 0; k < DIM; ++k) {
        float xk = bcast(xv, k);
        a0 = fmaf(w0[k], xk, a0);
        a1 = fmaf(w1[k], xk, a1);
        a2 = fmaf(w2[k], xk, a2);
    }
    float* gp = GI + b * G3;
    gp[lane] = a0; gp[DIM + lane] = a1; gp[2 * DIM + lane] = a2;
}

// ---------- fused0: block 0 = GRU hop0 (staged); blocks 1..512 = att hop0 + KGE + L2 ----------

__global__ __launch_bounds__(256, 1) void fused0(const float* __restrict__ E,
                                              const float* __restrict__ Rel,
                                              const int* __restrict__ items,
                                              const int* __restrict__ mh,
                                              const int* __restrict__ mr,
                                              const int* __restrict__ mt,
                                              const float* __restrict__ GI,
                                              const float* __restrict__ whh,
                                              const float* __restrict__ bhh,
                                              const float* __restrict__ relnorm,
                                              float* __restrict__ ys0,
                                              float* __restrict__ hfin,
                                              float* __restrict__ o0,
                                              float* __restrict__ kge_part,   // [NB][2]
                                              float* __restrict__ l2_part)    // [NB]
{
    __shared__ __align__(16) float gibuf[2][CH * G3];   // 48 KiB
    __shared__ __align__(16) float ysbuf[2][CH * DIM];  // 16 KiB
    __shared__ float logits[NM], probs[NM], opart[4][DIM], wred[4][4];

    if (blockIdx.x == 0) {
        gru_scan_staged(gibuf, ysbuf, GI, whh, bhh, nullptr, ys0, hfin);
        return;
    }

    const int b = blockIdx.x - 1;
    const int tid = threadIdx.x, lane = tid & 63, wave = tid >> 6;

    float iv = E[items[b] * DIM + lane];
    float kge0 = 0.0f, kge1 = 0.0f, l2acc = 0.0f, r2acc = 0.0f;

    for (int mm = 0; mm < 8; ++mm) {
        const int m = wave * 8 + mm;
        const int base = b * NM + m;                 // hop 0
        const int hidx = mh[base], ridx = mr[base], tidx = mt[base];
        float hv = E[hidx * DIM + lane];
        float tv = E[tidx * DIM + lane];
        l2acc = fmaf(hv, hv, l2acc);
        l2acc = fmaf(tv, tv, l2acc);
        r2acc += relnorm[ridx];
        const float* R = Rel + ridx * DIM * DIM;
        float accA = 0.0f, accK = 0.0f;
#pragma unroll 4
        for (int i = 0; i < DIM; ++i) {
            float rv = R[i * DIM + lane];
            accA = fmaf(bcast(iv, i), rv, accA);
            accK = fmaf(bcast(hv, i), rv, accK);
        }
        float la = wave_sum(accA * hv);              // item^T R h
        float lk = wave_sum(accK * tv);              // h^T R t
        if (lane == 0) logits[m] = la;
        kge0 += sigmoidf_(lk);
    }
    for (int mm = 0; mm < 8; ++mm) {
        const int m = wave * 8 + mm;
        const int base = NB * NM + b * NM + m;       // hop 1
        const int hidx = mh[base], ridx = mr[base], tidx = mt[base];
        float hv = E[hidx * DIM + lane];
        float tv = E[tidx * DIM + lane];
        l2acc = fmaf(hv, hv, l2acc);
        l2acc = fmaf(tv, tv, l2acc);
        r2acc += relnorm[ridx];
        const float* R = Rel + ridx * DIM * DIM;
        float accK = 0.0f;
#pragma unroll 4
        for (int i = 0; i < DIM; ++i)
            accK = fmaf(bcast(hv, i), R[i * DIM + lane], accK);
        kge1 += sigmoidf_(wave_sum(accK * tv));
    }
    __syncthreads();

    if (wave == 0) {
        float v = (lane < NM) ? logits[lane] : -1e30f;
        float mx = wave_max(v);
        float e = (lane < NM) ? __expf(v - mx) : 0.0f;
        float ssum = wave_sum(e);
        if (lane < NM) probs[lane] = e / ssum;
    }
    __syncthreads();

    float od = 0.0f;
    for (int mm = 0; mm < 8; ++mm) {
        const int m = wave * 8 + mm;
        const int tidx = mt[b * NM + m];
        od = fmaf(probs[m], E[tidx * DIM + lane], od);
    }
    opart[wave][lane] = od;
    float l2tot = wave_sum(l2acc);
    if (lane == 0) { wred[wave][0] = kge0; wred[wave][1] = kge1; wred[wave][2] = l2tot + r2acc; }
    __syncthreads();
    if (wave == 0)
        o0[b * DIM + lane] = opart[0][lane] + opart[1][lane] + opart[2][lane] + opart[3][lane];
    if (tid == 0) {
        kge_part[b * 2 + 0] = wred[0][0] + wred[1][0] + wred[2][0] + wred[3][0];
        kge_part[b * 2 + 1] = wred[0][1] + wred[1][1] + wred[2][1] + wred[3][1];
        l2_part[b]          = wred[0][2] + wred[1][2] + wred[2][2] + wred[3][2];
    }
}

// ---------- fused1: block 0 = GRU hop1 (staged); blocks 1..512 = att hop1 + o_sum ----------

__global__ __launch_bounds__(256, 1) void fused1(const float* __restrict__ E,
                                              const float* __restrict__ Rel,
                                              const int* __restrict__ mh,
                                              const int* __restrict__ mr,
                                              const int* __restrict__ mt,
                                              const float* __restrict__ GI,
                                              const float* __restrict__ whh,
                                              const float* __restrict__ bhh,
                                              const float* __restrict__ hfin,
                                              const float* __restrict__ ys0,
                                              float* __restrict__ ys1,
                                              const float* __restrict__ o0,
                                              float* __restrict__ osum)
{
    __shared__ __align__(16) float gibuf[2][CH * G3];   // 48 KiB
    __shared__ __align__(16) float ysbuf[2][CH * DIM];  // 16 KiB
    __shared__ float logits[NM], probs[NM], opart[4][DIM];

    if (blockIdx.x == 0) {
        gru_scan_staged(gibuf, ysbuf, GI, whh, bhh, hfin, ys1, nullptr);
        return;
    }

    const int b = blockIdx.x - 1;
    const int tid = threadIdx.x, lane = tid & 63, wave = tid >> 6;

    float iv = ys0[b * DIM + lane];   // item_emb after 1 GRU pass

    for (int mm = 0; mm < 8; ++mm) {
        const int m = wave * 8 + mm;
        const int base = NB * NM + b * NM + m;       // hop 1
        const int hidx = mh[base], ridx = mr[base];
        float hv = E[hidx * DIM + lane];
        const float* R = Rel + ridx * DIM * DIM;
        float accA = 0.0f;
#pragma unroll 4
        for (int i = 0; i < DIM; ++i)
            accA = fmaf(bcast(iv, i), R[i * DIM + lane], accA);
        float la = wave_sum(accA * hv);
        if (lane == 0) logits[m] = la;
    }
    __syncthreads();
    if (wave == 0) {
        float v = (lane < NM) ? logits[lane] : -1e30f;
        float mx = wave_max(v);
        float e = (lane < NM) ? __expf(v - mx) : 0.0f;
        float ssum = wave_sum(e);
        if (lane < NM) probs[lane] = e / ssum;
    }
    __syncthreads();
    float od = 0.0f;
    for (int mm = 0; mm < 8; ++mm) {
        const int m = wave * 8 + mm;
        const int tidx = mt[NB * NM + b * NM + m];
        od = fmaf(probs[m], E[tidx * DIM + lane], od);
    }
    opart[wave][lane] = od;
    __syncthreads();
    if (wave == 0)
        osum[b * DIM + lane] = o0[b * DIM + lane] +
            opart[0][lane] + opart[1][lane] + opart[2][lane] + opart[3][lane];
}

// ---------- finalize: scores + losses ----------

__global__ __launch_bounds__(512) void finalize(const float* __restrict__ ys1,
                                                const float* __restrict__ osum,
                                                const int* __restrict__ labels,
                                                const float* __restrict__ kge_part,
                                                const float* __restrict__ l2_part,
                                                float* __restrict__ out)
{
    __shared__ float red[512];
    const int tid = threadIdx.x;

    float dot = 0.0f;
    const float* a = ys1 + tid * DIM;
    const float* c = osum + tid * DIM;
#pragma unroll 8
    for (int k = 0; k < DIM; ++k) dot = fmaf(a[k], c[k], dot);
    float score = sigmoidf_(dot);
    out[tid] = score;

    float s = fminf(fmaxf(score, EPSC), 1.0f - EPSC);
    float term = labels[tid] ? logf(s) : log1pf(-s);

    float bsum, ksum, lsum;
    {
        red[tid] = term; __syncthreads();
#pragma unroll
        for (int st = 256; st > 0; st >>= 1) { if (tid < st) red[tid] += red[tid + st]; __syncthreads(); }
        bsum = red[0]; __syncthreads();
    }
    {
        red[tid] = kge_part[2 * tid] + kge_part[2 * tid + 1]; __syncthreads();
#pragma unroll
        for (int st = 256; st > 0; st >>= 1) { if (tid < st) red[tid] += red[tid + st]; __syncthreads(); }
        ksum = red[0]; __syncthreads();
    }
    {
        red[tid] = l2_part[tid]; __syncthreads();
#pragma unroll
        for (int st = 256; st > 0; st >>= 1) { if (tid < st) red[tid] += red[tid + st]; __syncthreads(); }
        lsum = red[0];
    }

    if (tid == 0) {
        float base = -bsum / (float)NB;
        float kge  = -KGE_W * ksum / (float)(NB * NM);
        float l2   = L2_W * lsum;
        out[NB + 0] = base;
        out[NB + 1] = kge;
        out[NB + 2] = l2;
        out[NB + 3] = base + kge + l2;
    }
}

// ---------- host ----------

extern "C" void kernel_launch(void* const* d_in, const int* in_sizes, int n_in,
                              void* d_out, int out_size, void* d_ws, size_t ws_size,
                              hipStream_t stream) {
    const int*   items  = (const int*)d_in[0];
    const int*   labels = (const int*)d_in[1];
    const int*   mh     = (const int*)d_in[2];
    const int*   mr     = (const int*)d_in[3];
    const int*   mt     = (const int*)d_in[4];
    const float* E      = (const float*)d_in[5];
    const float* Rel    = (const float*)d_in[6];
    const float* wih    = (const float*)d_in[7];
    const float* whh    = (const float*)d_in[8];
    const float* bih    = (const float*)d_in[9];
    const float* bhh    = (const float*)d_in[10];
    float* out = (float*)d_out;
    float* ws  = (float*)d_ws;

    // workspace layout (floats)
    float* GI0     = ws;                 // 512*192 = 98304
    float* GI1     = GI0 + 98304;        // 98304
    float* ys0     = GI1 + 98304;        // 32768
    float* ys1     = ys0 + 32768;        // 32768
    float* hfin    = ys1 + 32768;        // 64
    float* o0      = hfin + 64;          // 32768
    float* osum    = o0 + 32768;         // 32768
    float* relnorm = osum + 32768;       // 32
    float* kge_p   = relnorm + 32;       // 1024
    float* l2_p    = kge_p + 1024;       // 512

    // gi0: GI for hop 0 (x = entity_emb[items]) + per-relation sqnorms
    gi_kernel<<<NB + NRELS, 64, 0, stream>>>(E, items, wih, bih, Rel, GI0, relnorm);
    // fused0: GRU hop0 (block 0, LDS in/out staging) || att hop0 + KGE + L2
    fused0<<<NB + 1, 256, 0, stream>>>(E, Rel, items, mh, mr, mt, GI0, whh, bhh,
                                       relnorm, ys0, hfin, o0, kge_p, l2_p);
    // gi1: GI for hop 1 (x = ys0)
    gi_kernel<<<NB, 64, 0, stream>>>(ys0, nullptr, wih, bih, Rel, GI1, relnorm);
    // fused1: GRU hop1 (block 0, LDS in/out staging) || att hop1 + o_sum
    fused1<<<NB + 1, 256, 0, stream>>>(E, Rel, mh, mr, mt, GI1, whh, bhh, hfin,
                                       ys0, ys1, o0, osum);
    // finalize: scores + losses
    finalize<<<1, 512, 0, stream>>>(ys1, osum, labels, kge_p, l2_p, out);
}